// Round 24
// baseline (79.703 us; speedup 1.0000x reference)
//
#include <hip/hip_runtime.h>
#include <hip/hip_bf16.h>
#include <math.h>

typedef __bf16 bf16;
typedef __bf16 bf16x8 __attribute__((ext_vector_type(8)));
typedef float  f32x4  __attribute__((ext_vector_type(4)));
typedef uint32_t u32x2 __attribute__((ext_vector_type(2)));
typedef uint32_t u32x4 __attribute__((ext_vector_type(4)));

#define MFMA16(a, b, c) __builtin_amdgcn_mfma_f32_16x16x32_bf16((a), (b), (c), 0, 0, 0)

typedef const uint32_t __attribute__((address_space(1)))* gq_t;
typedef uint32_t __attribute__((address_space(3)))* lq_t;

constexpr int B_ = 8, C_ = 80, T_ = 2048, D_ = 256;
constexpr int NS = 8;                        // j-splits (grid 2048 = 8/CU disp.)
constexpr float LOG2E_16 = 0.090169989f;     // log2(e)/16

static __device__ inline uint32_t pkbf(float lo, float hi) {
  bf16 l = (bf16)lo, h = (bf16)hi;
  uint16_t lb = __builtin_bit_cast(uint16_t, l), hb = __builtin_bit_cast(uint16_t, h);
  return (uint32_t)lb | ((uint32_t)hb << 16);
}

// V fragment layout (16x16 PV A-operand): Vf[b][j32][cb(5)][lane(64)][e(8)],
// value = V[cb*16 + (l&15)][jt*32 + (l>>4)*8 + e].  C=80 = 5x16 exactly.
constexpr int VF_TILE = 5 * 64 * 8;          // 2560 bf16 = 5KB per 32-j tile

// ---------------------------------------------------------------------------
// Kernel 0: W+bias -> padded bf16 [2][256 d][96 c]. Grid (2 mats, 12 c8).
// ---------------------------------------------------------------------------
__global__ __launch_bounds__(256) void wconv_kernel(
    const float* __restrict__ Wk, const float* __restrict__ bk,
    const float* __restrict__ Wq, const float* __restrict__ bq,
    bf16* __restrict__ Wbf)        // [2][256][96]
{
  const int mat = blockIdx.x, c8 = blockIdx.y, d = threadIdx.x;
  const float* W    = mat ? Wq : Wk;
  const float* bias = mat ? bq : bk;
  bf16x8 o;
  #pragma unroll
  for (int e = 0; e < 8; ++e) {
    int c = c8 * 8 + e;
    float v = (c < 80) ? W[d * C_ + c] : (c == 80 ? bias[d] : 0.f);
    o[e] = (bf16)v;
  }
  *reinterpret_cast<bf16x8*>(Wbf + (size_t)(mat * 256 + d) * 96 + c8 * 8) = o;
}

// ---------------------------------------------------------------------------
// Kernel 1: projection, mats split across blockIdx.z (K=0 +Vf, Q=1).
// ---------------------------------------------------------------------------
__global__ __launch_bounds__(256) void proj_kernel(
    const float* __restrict__ x,   // [B][C][T]
    const bf16* __restrict__ Wbf,  // [2][256][96]
    bf16* __restrict__ Kb,         // [B][T][D]
    bf16* __restrict__ Qb,         // [B][T][D]
    bf16* __restrict__ Vf)         // [B][64][VF_TILE]
{
  const int t0   = blockIdx.x * 32;   // 32-j tile index = blockIdx.x
  const int b    = blockIdx.y;
  const int mat  = blockIdx.z;        // 0 = K (+Vf), 1 = Q
  const int tid  = threadIdx.x;
  const int w    = tid >> 6;
  const int lane = tid & 63;
  const int h    = lane >> 4;
  const int lr   = lane & 15;

  const float* xb = x + (size_t)b * C_ * T_;

  // --- V fragments for this 32-j tile (K-half blocks only): 320 chunks ---
  if (mat == 0) {
    bf16* vout = Vf + (size_t)(b * 64 + blockIdx.x) * VF_TILE;
    #pragma unroll
    for (int g = 0; g < 2; ++g) {
      int f = tid + g * 256;
      if (f < 320) {
        int l2 = f & 63, cb2 = f >> 6;
        int c = cb2 * 16 + (l2 & 15);             // < 80 always
        const float* sp = xb + (size_t)c * T_ + t0 + ((l2 >> 4) << 3);
        f32x4 v0 = *reinterpret_cast<const f32x4*>(sp);
        f32x4 v1 = *reinterpret_cast<const f32x4*>(sp + 4);
        bf16x8 o;
        #pragma unroll
        for (int e = 0; e < 4; ++e) { o[e] = (bf16)v0[e]; o[e + 4] = (bf16)v1[e]; }
        *reinterpret_cast<bf16x8*>(vout + f * 8) = o;
      }
    }
  }

  // A-fragments: xt rows t0..t0+31, c padded to 96
  bf16x8 afrag[2][3];
  #pragma unroll
  for (int ib = 0; ib < 2; ++ib) {
    int t = t0 + ib * 16 + lr;
    #pragma unroll
    for (int ks = 0; ks < 3; ++ks) {
      bf16x8 v;
      #pragma unroll
      for (int e = 0; e < 8; ++e) {
        int c = ks * 32 + h * 8 + e;
        float val;
        if (c < 80)       val = xb[c * T_ + t];
        else if (c == 80) val = 1.0f;
        else              val = 0.0f;
        v[e] = (bf16)val;
      }
      afrag[ib][ks] = v;
    }
  }

  const int nb0 = w * 4;
  bf16* outp = mat ? Qb : Kb;

  f32x4 acc[2][4];
  #pragma unroll
  for (int ib = 0; ib < 2; ++ib)
    #pragma unroll
    for (int nb = 0; nb < 4; ++nb)
      acc[ib][nb] = f32x4{0.f, 0.f, 0.f, 0.f};

  #pragma unroll
  for (int nb = 0; nb < 4; ++nb) {
    int d = (nb0 + nb) * 16 + lr;
    const bf16* wrow = Wbf + (size_t)(mat * 256 + d) * 96;
    #pragma unroll
    for (int ks = 0; ks < 3; ++ks) {
      bf16x8 bv = *reinterpret_cast<const bf16x8*>(wrow + ks * 32 + h * 8);
      #pragma unroll
      for (int ib = 0; ib < 2; ++ib)
        acc[ib][nb] = MFMA16(afrag[ib][ks], bv, acc[ib][nb]);
    }
  }

  #pragma unroll
  for (int ib = 0; ib < 2; ++ib)
    #pragma unroll
    for (int nb = 0; nb < 4; ++nb) {
      int d = (nb0 + nb) * 16 + lr;
      #pragma unroll
      for (int r = 0; r < 4; ++r) {
        int t = t0 + ib * 16 + h * 4 + r;
        outp[(size_t)(b * T_ + t) * D_ + d] = (bf16)acc[ib][nb][r];
      }
    }
}

// ---------------------------------------------------------------------------
// Kernel 2: flash attention, 16x16-MFMA reshape (R23, VGPR 72, validated),
// now with NS=8 to feed its occupancy headroom: grid 2048 = 8 blocks/CU
// dispatched, 5 resident (LDS 32KB cap) vs R23's grid-capped 4.
// ---------------------------------------------------------------------------
__global__ __launch_bounds__(256, 3) void attn_kernel(
    const bf16* __restrict__ Kb,   // [B][T][D]
    const bf16* __restrict__ Qb,   // [B][T][D]
    const bf16* __restrict__ Vf,   // [B][64][VF_TILE]
    float* __restrict__ Opart,     // [NS][B][C][T]
    float* __restrict__ mpart,     // [NS][B][T]
    float* __restrict__ lpart)     // [NS][B][T]
{
  constexpr int BN = 32, NSTG = T_ / BN;   // 64 staged 32-j tiles
  constexpr int STG_PER = NSTG / NS;       // 8 per split
  __shared__ bf16 qlds[2][BN * D_];        // 2 x 16 KB

  const int flat = blockIdx.x;
  const int b    = flat & 7;               // batch -> XCD
  const int rem  = flat >> 3;
  const int it   = rem & 31;               // 32 i-tiles of 64
  const int s    = rem >> 5;               // split 0..7
  const int i0   = it * 64;

  const int tid  = threadIdx.x;
  const int w    = tid >> 6;
  const int lane = tid & 63;
  const int li   = lane & 15;              // i within wave tile / A-row / B-col
  const int g    = lane >> 4;              // 0..3 lane group
  const int iw   = i0 + w * 16;            // this wave's 16 i-rows

  const bf16* Kbase = Kb + (size_t)b * T_ * D_;
  const bf16* Qbase = Qb + (size_t)b * T_ * D_;
  const bf16* Vbase = Vf + (size_t)b * 64 * VF_TILE;

  // K B-frags (resident, 32 VGPR): kf[ks][e] = K[iw+li][ks*32 + g*8 + e]
  bf16x8 kf[8];
  {
    const bf16* kp = Kbase + (size_t)(iw + li) * D_ + g * 8;
    #pragma unroll
    for (int ks = 0; ks < 8; ++ks)
      kf[ks] = *reinterpret_cast<const bf16x8*>(kp + ks * 32);
  }

  f32x4 oacc[5];
  #pragma unroll
  for (int cb = 0; cb < 5; ++cb) oacc[cb] = f32x4{0.f, 0.f, 0.f, 0.f};
  float m_run = -INFINITY, l_run = 0.f;    // l_run: per-lane partial

  const int st0 = s * STG_PER;
  const int off = it & 7;                  // stagger (j-order-invariant)
  auto smap = [&](int t) { return st0 + ((t - st0 + off) & (STG_PER - 1)); };

  // Stage one 32-j Q tile (swizzled source -> linear LDS dest).
  auto stage = [&](int st, int buf) {
    #pragma unroll
    for (int q = 0; q < 4; ++q) {
      int f = tid + 256 * q;               // 16B-chunk id, 0..1023
      int j = f >> 5, c = f & 31;
      const bf16* src = Qbase + (size_t)(st * BN + j) * D_ + ((c ^ j) << 3);
      __builtin_amdgcn_global_load_lds((gq_t)src,
          (lq_t)&qlds[buf][(q * 256 + w * 64) * 8], 16, 0, 0);
    }
  };

  stage(smap(st0), 0);
  asm volatile("s_waitcnt vmcnt(0)" ::: "memory");
  __syncthreads();

  int cur = 0;
  for (int t = st0; t < st0 + STG_PER; ++t, cur ^= 1) {
    const int st = smap(t);
    if (t + 1 < st0 + STG_PER) stage(smap(t + 1), cur ^ 1);

    // V A-frags (1KB contiguous per cb): vf[cb][e] = V[cb*16+li][st*32+g*8+e]
    const bf16* vt = Vbase + (size_t)st * VF_TILE + lane * 8;
    bf16x8 vf[5];
    #pragma unroll
    for (int cb = 0; cb < 5; ++cb)
      vf[cb] = *reinterpret_cast<const bf16x8*>(vt + cb * 512);

    // --- S^T = Q K^T: two independent 8-deep chains (j-halves) ---
    f32x4 sacc_a = f32x4{0.f, 0.f, 0.f, 0.f};
    f32x4 sacc_b = f32x4{0.f, 0.f, 0.f, 0.f};
    __builtin_amdgcn_s_setprio(1);
    #pragma unroll
    for (int ks = 0; ks < 8; ++ks) {
      const int chunk = ks * 4 + g;
      bf16x8 qa0 = *reinterpret_cast<const bf16x8*>(
          &qlds[cur][li * 256 + ((chunk ^ li) << 3)]);
      bf16x8 qa1 = *reinterpret_cast<const bf16x8*>(
          &qlds[cur][(16 + li) * 256 + ((chunk ^ (16 + li)) << 3)]);
      sacc_a = MFMA16(qa0, kf[ks], sacc_a);
      sacc_b = MFMA16(qa1, kf[ks], sacc_b);
    }
    __builtin_amdgcn_s_setprio(0);

    // --- softmax: lane holds j = {4g..4g+3} u {16+4g..+3} of row i=iw+li ---
    float p8[8];
    #pragma unroll
    for (int r = 0; r < 4; ++r) { p8[r] = sacc_a[r]; p8[4 + r] = sacc_b[r]; }
    float mx = fmaxf(fmaxf(fmaxf(p8[0], p8[1]), fmaxf(p8[2], p8[3])),
                     fmaxf(fmaxf(p8[4], p8[5]), fmaxf(p8[6], p8[7])));
    mx = fmaxf(mx, __shfl_xor(mx, 16));
    mx = fmaxf(mx, __shfl_xor(mx, 32));

    // defer-max (T13): raw threshold 48 = 3 score units (P <= e^3)
    if (!__all(mx <= m_run + 48.f)) {
      float mnew  = fmaxf(m_run, mx);
      float alpha = exp2f((m_run - mnew) * LOG2E_16);
      m_run = mnew;
      l_run *= alpha;
      #pragma unroll
      for (int cb = 0; cb < 5; ++cb)
        #pragma unroll
        for (int r = 0; r < 4; ++r) oacc[cb][r] *= alpha;
    }
    #pragma unroll
    for (int r = 0; r < 8; ++r)
      p8[r] = exp2f((p8[r] - m_run) * LOG2E_16);
    l_run += ((p8[0] + p8[1]) + (p8[2] + p8[3])) +
             ((p8[4] + p8[5]) + (p8[6] + p8[7]));   // per-lane partial

    // --- P -> bf16 B-frag: lane needs P[8g+e][i], e=0..7.
    //     (dw0,dw2) = pl16swap(pl32swap(A0,B0)); (dw1,dw3) likewise. ---
    uint32_t A0 = pkbf(p8[0], p8[1]), A1 = pkbf(p8[2], p8[3]);
    uint32_t B0 = pkbf(p8[4], p8[5]), B1 = pkbf(p8[6], p8[7]);
    u32x2 sw0 = __builtin_amdgcn_permlane32_swap(A0, B0, false, false);
    u32x2 tw0 = __builtin_amdgcn_permlane16_swap(sw0[0], sw0[1], false, false);
    u32x2 sw1 = __builtin_amdgcn_permlane32_swap(A1, B1, false, false);
    u32x2 tw1 = __builtin_amdgcn_permlane16_swap(sw1[0], sw1[1], false, false);
    u32x4 pb = { tw0[0], tw1[0], tw0[1], tw1[1] };
    bf16x8 pbf = __builtin_bit_cast(bf16x8, pb);

    // --- PV: oacc[cb] += V^T[cb-tile] . P  (5 exact 16-row c-tiles) ---
    __builtin_amdgcn_s_setprio(1);
    #pragma unroll
    for (int cb = 0; cb < 5; ++cb)
      oacc[cb] = MFMA16(vf[cb], pbf, oacc[cb]);
    __builtin_amdgcn_s_setprio(0);

    asm volatile("s_waitcnt vmcnt(0)" ::: "memory");  // next stage landed
    __syncthreads();
  }

  l_run += __shfl_xor(l_run, 16);       // combine the 4 lane groups
  l_run += __shfl_xor(l_run, 32);

  // --- epilogue: unnormalized partials. oacc[cb][r] = O^T[cb*16+4g+r][iw+li]
  float* ob = Opart + (size_t)(s * B_ + b) * C_ * T_;
  #pragma unroll
  for (int cb = 0; cb < 5; ++cb)
    #pragma unroll
    for (int r = 0; r < 4; ++r) {
      int c = cb * 16 + g * 4 + r;
      ob[(size_t)c * T_ + iw + li] = oacc[cb][r];
    }
  if (lane < 16) {
    mpart[(size_t)(s * B_ + b) * T_ + iw + lane] = m_run;
    lpart[(size_t)(s * B_ + b) * T_ + iw + lane] = l_run;
  }
}

// ---------------------------------------------------------------------------
// Kernel 3: merge splits (NS=8), f32x4-vectorized, 1024 blocks.
// ---------------------------------------------------------------------------
__global__ __launch_bounds__(256) void merge_kernel(
    const float* __restrict__ Opart,  // [NS][B][C][T]
    const float* __restrict__ mpart,  // [NS][B][T]
    const float* __restrict__ lpart,  // [NS][B][T]
    float* __restrict__ out)          // [B][C][T]
{
  const int b    = blockIdx.y;
  const int tid  = threadIdx.x;
  const int slot = tid & 3;
  const int c1   = tid >> 2;           // 0..63
  const int t4   = blockIdx.x * 16 + slot * 4;

  f32x4 m[NS], e[NS];
  f32x4 mmax;
  #pragma unroll
  for (int s2 = 0; s2 < NS; ++s2)
    m[s2] = *reinterpret_cast<const f32x4*>(&mpart[(size_t)(s2 * B_ + b) * T_ + t4]);
  #pragma unroll
  for (int r = 0; r < 4; ++r) {
    mmax[r] = m[0][r];
    #pragma unroll
    for (int s2 = 1; s2 < NS; ++s2) mmax[r] = fmaxf(mmax[r], m[s2][r]);
  }
  f32x4 lsum = f32x4{0.f, 0.f, 0.f, 0.f};
  #pragma unroll
  for (int s2 = 0; s2 < NS; ++s2) {
    f32x4 lv = *reinterpret_cast<const f32x4*>(&lpart[(size_t)(s2 * B_ + b) * T_ + t4]);
    #pragma unroll
    for (int r = 0; r < 4; ++r) e[s2][r] = exp2f((m[s2][r] - mmax[r]) * LOG2E_16);
    lsum += e[s2] * lv;
  }
  f32x4 inv;
  #pragma unroll
  for (int r = 0; r < 4; ++r) inv[r] = 1.0f / lsum[r];

  #pragma unroll
  for (int pass = 0; pass < 2; ++pass) {
    const int c = c1 + pass * 64;
    if (pass == 0 || c1 < 16) {
      f32x4 acc = f32x4{0.f, 0.f, 0.f, 0.f};
      #pragma unroll
      for (int s2 = 0; s2 < NS; ++s2)
        acc += *reinterpret_cast<const f32x4*>(
                   &Opart[((size_t)(s2 * B_ + b) * C_ + c) * T_ + t4]) * e[s2];
      *reinterpret_cast<f32x4*>(&out[((size_t)b * C_ + c) * T_ + t4]) = acc * inv;
    }
  }
}

// ---------------------------------------------------------------------------
extern "C" void kernel_launch(void* const* d_in, const int* in_sizes, int n_in,
                              void* d_out, int out_size, void* d_ws, size_t ws_size,
                              hipStream_t stream) {
  (void)in_sizes; (void)n_in; (void)out_size; (void)ws_size;
  const float* x  = (const float*)d_in[0];
  const float* Wk = (const float*)d_in[1];
  const float* bk = (const float*)d_in[2];
  const float* Wq = (const float*)d_in[3];
  const float* bq = (const float*)d_in[4];
  float* out = (float*)d_out;

  char* ws = (char*)d_ws;
  const size_t MB = 1024 * 1024;
  bf16*  Kb    = (bf16*)(ws);                 // 8 MB
  bf16*  Qb    = (bf16*)(ws + 8 * MB);        // 8 MB
  bf16*  Vf    = (bf16*)(ws + 16 * MB);       // 2.5 MB (16x16 frag layout)
  bf16*  Wbf   = (bf16*)(ws + 19 * MB);       // 96 KB
  float* Opart = (float*)(ws + 20 * MB);      // NS*8*80*2048*4 = 41.94 MB
  float* mpart = (float*)(ws + 63 * MB);      // 512 KB
  float* lpart = (float*)(ws + 64 * MB);      // 512 KB

  dim3 blk(256);
  wconv_kernel<<<dim3(2, 12), blk, 0, stream>>>(Wk, bk, Wq, bq, Wbf);
  dim3 g1(T_ / 32, B_, 2);
  proj_kernel<<<g1, blk, 0, stream>>>(x, Wbf, Kb, Qb, Vf);
  attn_kernel<<<dim3(32 * NS * B_), blk, 0, stream>>>(Kb, Qb, Vf, Opart, mpart, lpart);
  dim3 g3(T_ / 16, B_);
  merge_kernel<<<g3, blk, 0, stream>>>(Opart, mpart, lpart, out);
}

// Round 25
// 62.393 us; speedup vs baseline: 1.2774x; 1.2774x over previous
//
#include <hip/hip_runtime.h>
#include <hip/hip_bf16.h>
#include <math.h>

typedef __bf16 bf16;
typedef __bf16 bf16x8 __attribute__((ext_vector_type(8)));
typedef float  f32x4  __attribute__((ext_vector_type(4)));
typedef float  f32x16 __attribute__((ext_vector_type(16)));
typedef uint32_t u32x2 __attribute__((ext_vector_type(2)));
typedef uint32_t u32x4 __attribute__((ext_vector_type(4)));

#define MFMA16(a, b, c) __builtin_amdgcn_mfma_f32_16x16x32_bf16((a), (b), (c), 0, 0, 0)
#define MFMA32(a, b, c) __builtin_amdgcn_mfma_f32_32x32x16_bf16((a), (b), (c), 0, 0, 0)

typedef const uint32_t __attribute__((address_space(1)))* gq_t;
typedef uint32_t __attribute__((address_space(3)))* lq_t;

constexpr int B_ = 8, C_ = 80, T_ = 2048, D_ = 256;
constexpr int NS = 4;                        // j-splits
constexpr float LOG2E_16 = 0.090169989f;     // log2(e)/16

static __device__ inline uint32_t pkbf(float lo, float hi) {
  bf16 l = (bf16)lo, h = (bf16)hi;
  uint16_t lb = __builtin_bit_cast(uint16_t, l), hb = __builtin_bit_cast(uint16_t, h);
  return (uint32_t)lb | ((uint32_t)hb << 16);
}

// V fragment layout: Vf[b][j32][cb][kj][hi][il][e], value =
//   V[cb*32+il][j32*32 + hi*8 + kj*16 + e]  (zeros for c>=80)
constexpr int VF_TILE = 3 * 2 * 2 * 32 * 8;  // 3072 bf16 = 6KB per 32-j tile

// ---------------------------------------------------------------------------
// Kernel 0: W+bias -> padded bf16 [2][256 d][96 c]. Grid (2 mats, 12 c8).
// ---------------------------------------------------------------------------
__global__ __launch_bounds__(256) void wconv_kernel(
    const float* __restrict__ Wk, const float* __restrict__ bk,
    const float* __restrict__ Wq, const float* __restrict__ bq,
    bf16* __restrict__ Wbf)        // [2][256][96]
{
  const int mat = blockIdx.x, c8 = blockIdx.y, d = threadIdx.x;
  const float* W    = mat ? Wq : Wk;
  const float* bias = mat ? bq : bk;
  bf16x8 o;
  #pragma unroll
  for (int e = 0; e < 8; ++e) {
    int c = c8 * 8 + e;
    float v = (c < 80) ? W[d * C_ + c] : (c == 80 ? bias[d] : 0.f);
    o[e] = (bf16)v;
  }
  *reinterpret_cast<bf16x8*>(Wbf + (size_t)(mat * 256 + d) * 96 + c8 * 8) = o;
}

// ---------------------------------------------------------------------------
// Kernel 1: projection, mats split across blockIdx.z (K=0 +Vf, Q=1).
// ---------------------------------------------------------------------------
__global__ __launch_bounds__(256) void proj_kernel(
    const float* __restrict__ x,   // [B][C][T]
    const bf16* __restrict__ Wbf,  // [2][256][96]
    bf16* __restrict__ Kb,         // [B][T][D]
    bf16* __restrict__ Qb,         // [B][T][D]
    bf16* __restrict__ Vf)         // [B][64][VF_TILE]
{
  const int t0   = blockIdx.x * 32;   // 32-j tile index = blockIdx.x
  const int b    = blockIdx.y;
  const int mat  = blockIdx.z;        // 0 = K (+Vf), 1 = Q
  const int tid  = threadIdx.x;
  const int w    = tid >> 6;
  const int lane = tid & 63;
  const int h    = lane >> 4;
  const int lr   = lane & 15;

  const float* xb = x + (size_t)b * C_ * T_;

  // --- V fragments for this 32-j tile (K-half blocks only) ---
  if (mat == 0) {
    bf16* vout = Vf + (size_t)(b * 64 + blockIdx.x) * VF_TILE;
    #pragma unroll
    for (int g = 0; g < 2; ++g) {
      int f = tid + g * 256;
      if (f < 384) {
        int il2 = f & 31, hi2 = (f >> 5) & 1, kj2 = (f >> 6) & 1, cb2 = f >> 7;
        int c = cb2 * 32 + il2;
        bf16x8 o;
        if (c < 80) {
          const float* sp = xb + (size_t)c * T_ + t0 + kj2 * 16 + hi2 * 8;
          f32x4 v0 = *reinterpret_cast<const f32x4*>(sp);
          f32x4 v1 = *reinterpret_cast<const f32x4*>(sp + 4);
          #pragma unroll
          for (int e = 0; e < 4; ++e) { o[e] = (bf16)v0[e]; o[e + 4] = (bf16)v1[e]; }
        } else {
          #pragma unroll
          for (int e = 0; e < 8; ++e) o[e] = (bf16)0.f;
        }
        *reinterpret_cast<bf16x8*>(vout + f * 8) = o;
      }
    }
  }

  // A-fragments: xt rows t0..t0+31, c padded to 96
  bf16x8 afrag[2][3];
  #pragma unroll
  for (int ib = 0; ib < 2; ++ib) {
    int t = t0 + ib * 16 + lr;
    #pragma unroll
    for (int ks = 0; ks < 3; ++ks) {
      bf16x8 v;
      #pragma unroll
      for (int e = 0; e < 8; ++e) {
        int c = ks * 32 + h * 8 + e;
        float val;
        if (c < 80)       val = xb[c * T_ + t];
        else if (c == 80) val = 1.0f;
        else              val = 0.0f;
        v[e] = (bf16)val;
      }
      afrag[ib][ks] = v;
    }
  }

  const int nb0 = w * 4;
  bf16* outp = mat ? Qb : Kb;

  f32x4 acc[2][4];
  #pragma unroll
  for (int ib = 0; ib < 2; ++ib)
    #pragma unroll
    for (int nb = 0; nb < 4; ++nb)
      acc[ib][nb] = f32x4{0.f, 0.f, 0.f, 0.f};

  #pragma unroll
  for (int nb = 0; nb < 4; ++nb) {
    int d = (nb0 + nb) * 16 + lr;
    const bf16* wrow = Wbf + (size_t)(mat * 256 + d) * 96;
    #pragma unroll
    for (int ks = 0; ks < 3; ++ks) {
      bf16x8 bv = *reinterpret_cast<const bf16x8*>(wrow + ks * 32 + h * 8);
      #pragma unroll
      for (int ib = 0; ib < 2; ++ib)
        acc[ib][nb] = MFMA16(afrag[ib][ks], bv, acc[ib][nb]);
    }
  }

  #pragma unroll
  for (int ib = 0; ib < 2; ++ib)
    #pragma unroll
    for (int nb = 0; nb < 4; ++nb) {
      int d = (nb0 + nb) * 16 + lr;
      #pragma unroll
      for (int r = 0; r < 4; ++r) {
        int t = t0 + ib * 16 + h * 4 + r;
        outp[(size_t)(b * T_ + t) * D_ + d] = (bf16)acc[ib][nb][r];
      }
    }
}

// ---------------------------------------------------------------------------
// Kernel 2: flash attention (measured-best structure). Swapped-QK 32x32,
// BN=64 staging, sequential sub-tiles, permlane32_swap P-exchange, max3.
// launch_bounds(256,2): ~170-reg class does NOT fit 3 waves (R16/R19 spill).
// ---------------------------------------------------------------------------
__global__ __launch_bounds__(256, 2) void attn_kernel(
    const bf16* __restrict__ Kb,   // [B][T][D]
    const bf16* __restrict__ Qb,   // [B][T][D]
    const bf16* __restrict__ Vf,   // [B][64][VF_TILE]
    float* __restrict__ Opart,     // [NS][B][C][T]
    float* __restrict__ mpart,     // [NS][B][T]
    float* __restrict__ lpart)     // [NS][B][T]
{
  constexpr int BN = 64, NSTG = T_ / BN;   // 32 staged 64-j tiles
  constexpr int STG_PER = NSTG / NS;       // 8 per split
  __shared__ bf16 qlds[2][BN * D_];        // 2 x 32 KB

  const int flat = blockIdx.x;
  const int b    = flat & 7;               // batch -> XCD
  const int rem  = flat >> 3;
  const int it   = rem & 15;               // 16 i-tiles of 128
  const int s    = rem >> 4;               // split 0..3
  const int i0   = it * 128;

  const int tid  = threadIdx.x;
  const int w    = tid >> 6;
  const int lane = tid & 63;
  const int il   = lane & 31;
  const int hi   = lane >> 5;
  const int iw   = i0 + w * 32;            // this wave's 32 i-rows

  const bf16* Kbase = Kb + (size_t)b * T_ * D_;
  const bf16* Qbase = Qb + (size_t)b * T_ * D_;
  const bf16* Vbase = Vf + (size_t)b * 64 * VF_TILE;

  // K B-frags (resident): kf[ks] = K[iw+il][hi*8 + ks*16 .. +7]
  bf16x8 kf[16];
  {
    const bf16* kp = Kbase + (size_t)(iw + il) * D_ + hi * 8;
    #pragma unroll
    for (int ks = 0; ks < 16; ++ks)
      kf[ks] = *reinterpret_cast<const bf16x8*>(kp + ks * 16);
  }

  f32x16 oacc[3];
  #pragma unroll
  for (int cb = 0; cb < 3; ++cb)
    #pragma unroll
    for (int r = 0; r < 16; ++r) oacc[cb][r] = 0.f;
  float m_run = -INFINITY, l_run = 0.f;    // l_run: per-half partial

  const int st0 = s * STG_PER;
  const int off = (it & 3) * 2;            // stagger (j-order-invariant)
  auto smap = [&](int t) { return st0 + ((t - st0 + off) & (STG_PER - 1)); };

  // Stage one 64-j Q tile (swizzled source -> linear LDS dest).
  auto stage = [&](int st, int buf) {
    #pragma unroll
    for (int q = 0; q < 8; ++q) {
      int f = tid + 256 * q;               // 16B-chunk id, 0..2047
      int j = f >> 5, c = f & 31;
      const bf16* src = Qbase + (size_t)(st * BN + j) * D_ + ((c ^ (j & 31)) << 3);
      __builtin_amdgcn_global_load_lds((gq_t)src,
          (lq_t)&qlds[buf][(q * 256 + w * 64) * 8], 16, 0, 0);
    }
  };

  stage(smap(st0), 0);
  asm volatile("s_waitcnt vmcnt(0)" ::: "memory");
  __syncthreads();

  int cur = 0;
  for (int t = st0; t < st0 + STG_PER; ++t, cur ^= 1) {
    const int st = smap(t);
    if (t + 1 < st0 + STG_PER) stage(smap(t + 1), cur ^ 1);

    #pragma unroll
    for (int hf = 0; hf < 2; ++hf) {
      const int j32 = st * 2 + hf;         // global 32-j tile index

      // V^T A-frags direct from global frag layout (64-lane-contiguous 1KB)
      const bf16* vt = Vbase + (size_t)j32 * VF_TILE + lane * 8;
      bf16x8 vf[3][2];
      #pragma unroll
      for (int cb = 0; cb < 3; ++cb)
        #pragma unroll
        for (int kj = 0; kj < 2; ++kj)
          vf[cb][kj] = *reinterpret_cast<const bf16x8*>(vt + (cb * 2 + kj) * 512);

      // --- S^T = Q K^T over this 32-j sub-tile ---
      f32x16 sacc;
      #pragma unroll
      for (int r = 0; r < 16; ++r) sacc[r] = 0.f;
      __builtin_amdgcn_s_setprio(1);
      #pragma unroll
      for (int ks = 0; ks < 16; ++ks) {
        bf16x8 qa = *reinterpret_cast<const bf16x8*>(
            &qlds[cur][(hf * 32 + il) * 256 + (((hi + 2 * ks) ^ il) << 3)]);
        sacc = MFMA32(qa, kf[ks], sacc);
      }
      __builtin_amdgcn_s_setprio(0);

      // --- in-register online softmax (exp2-folded, max3 tree) ---
      float p16[16];
      #pragma unroll
      for (int r = 0; r < 16; ++r) p16[r] = sacc[r];
      float q0 = fmaxf(fmaxf(p16[0],  p16[1]),  p16[2]);
      float q1 = fmaxf(fmaxf(p16[3],  p16[4]),  p16[5]);
      float q2 = fmaxf(fmaxf(p16[6],  p16[7]),  p16[8]);
      float q3 = fmaxf(fmaxf(p16[9],  p16[10]), p16[11]);
      float q4 = fmaxf(fmaxf(p16[12], p16[13]), p16[14]);
      float mx = fmaxf(fmaxf(fmaxf(q0, q1), q2),
                       fmaxf(fmaxf(q3, q4), p16[15]));
      mx = fmaxf(mx, __shfl_xor(mx, 32));

      // defer-max (T13): raw threshold 48 = 3 score units (P <= e^3)
      if (!__all(mx <= m_run + 48.f)) {
        float mnew  = fmaxf(m_run, mx);
        float alpha = exp2f((m_run - mnew) * LOG2E_16);
        m_run = mnew;
        l_run *= alpha;
        #pragma unroll
        for (int cb = 0; cb < 3; ++cb)
          #pragma unroll
          for (int r = 0; r < 16; ++r) oacc[cb][r] *= alpha;
      }
      #pragma unroll
      for (int r = 0; r < 16; ++r)
        p16[r] = exp2f((p16[r] - m_run) * LOG2E_16);
      {
        float s0 = (p16[0] + p16[1]) + (p16[2] + p16[3]);
        float s1 = (p16[4] + p16[5]) + (p16[6] + p16[7]);
        float s2 = (p16[8] + p16[9]) + (p16[10] + p16[11]);
        float s3 = (p16[12] + p16[13]) + (p16[14] + p16[15]);
        l_run += (s0 + s1) + (s2 + s3);   // per-half partial
      }

      // --- P -> bf16 B-frags via permlane32_swap (T12) ---
      uint32_t a0 = pkbf(p16[0],  p16[1]),  a1 = pkbf(p16[2],  p16[3]);
      uint32_t c0 = pkbf(p16[4],  p16[5]),  c1 = pkbf(p16[6],  p16[7]);
      uint32_t a2 = pkbf(p16[8],  p16[9]),  a3 = pkbf(p16[10], p16[11]);
      uint32_t c2 = pkbf(p16[12], p16[13]), c3 = pkbf(p16[14], p16[15]);
      u32x2 w0 = __builtin_amdgcn_permlane32_swap(a0, c0, false, false);
      u32x2 w1 = __builtin_amdgcn_permlane32_swap(a1, c1, false, false);
      u32x2 w2 = __builtin_amdgcn_permlane32_swap(a2, c2, false, false);
      u32x2 w3 = __builtin_amdgcn_permlane32_swap(a3, c3, false, false);
      u32x4 pb0 = { w0[0], w1[0], w0[1], w1[1] };
      u32x4 pb1 = { w2[0], w3[0], w2[1], w3[1] };
      bf16x8 pbf0 = __builtin_bit_cast(bf16x8, pb0);
      bf16x8 pbf1 = __builtin_bit_cast(bf16x8, pb1);

      // --- PV: oacc[cb] += V^T[cb] . P ---
      __builtin_amdgcn_s_setprio(1);
      #pragma unroll
      for (int cb = 0; cb < 3; ++cb) {
        oacc[cb] = MFMA32(vf[cb][0], pbf0, oacc[cb]);
        oacc[cb] = MFMA32(vf[cb][1], pbf1, oacc[cb]);
      }
      __builtin_amdgcn_s_setprio(0);
    }

    asm volatile("s_waitcnt vmcnt(0)" ::: "memory");  // next stage landed
    __syncthreads();
  }

  l_run += __shfl_xor(l_run, 32);       // combine halves once

  // --- epilogue: unnormalized partials ---
  float* ob = Opart + (size_t)(s * B_ + b) * C_ * T_;
  #pragma unroll
  for (int cb = 0; cb < 3; ++cb)
    #pragma unroll
    for (int r = 0; r < 16; ++r) {
      if (cb < 2 || r < 8) {
        int c = cb * 32 + (r & 3) + 8 * (r >> 2) + 4 * hi;
        ob[(size_t)c * T_ + iw + il] = oacc[cb][r];
      }
    }
  if (lane < 32) {
    mpart[(size_t)(s * B_ + b) * T_ + iw + il] = m_run;
    lpart[(size_t)(s * B_ + b) * T_ + iw + il] = l_run;
  }
}

// ---------------------------------------------------------------------------
// Kernel 3: merge splits, f32x4-vectorized, grid (T/64, B).
// ---------------------------------------------------------------------------
__global__ __launch_bounds__(256) void merge_kernel(
    const float* __restrict__ Opart,  // [NS][B][C][T]
    const float* __restrict__ mpart,  // [NS][B][T]
    const float* __restrict__ lpart,  // [NS][B][T]
    float* __restrict__ out)          // [B][C][T]
{
  const int b      = blockIdx.y;
  const int tid    = threadIdx.x;
  const int slot   = tid & 15;
  const int cstrip = tid >> 4;
  const int t4     = blockIdx.x * 64 + slot * 4;

  f32x4 m[NS], e[NS];
  f32x4 mmax;
  #pragma unroll
  for (int s2 = 0; s2 < NS; ++s2)
    m[s2] = *reinterpret_cast<const f32x4*>(&mpart[(size_t)(s2 * B_ + b) * T_ + t4]);
  #pragma unroll
  for (int r = 0; r < 4; ++r) {
    mmax[r] = m[0][r];
    #pragma unroll
    for (int s2 = 1; s2 < NS; ++s2) mmax[r] = fmaxf(mmax[r], m[s2][r]);
  }
  f32x4 lsum = f32x4{0.f, 0.f, 0.f, 0.f};
  #pragma unroll
  for (int s2 = 0; s2 < NS; ++s2) {
    f32x4 lv = *reinterpret_cast<const f32x4*>(&lpart[(size_t)(s2 * B_ + b) * T_ + t4]);
    #pragma unroll
    for (int r = 0; r < 4; ++r) e[s2][r] = exp2f((m[s2][r] - mmax[r]) * LOG2E_16);
    lsum += e[s2] * lv;
  }
  f32x4 inv;
  #pragma unroll
  for (int r = 0; r < 4; ++r) inv[r] = 1.0f / lsum[r];

  #pragma unroll
  for (int cc = 0; cc < 5; ++cc) {
    const int c = cstrip * 5 + cc;
    f32x4 acc = f32x4{0.f, 0.f, 0.f, 0.f};
    #pragma unroll
    for (int s2 = 0; s2 < NS; ++s2)
      acc += *reinterpret_cast<const f32x4*>(
                 &Opart[((size_t)(s2 * B_ + b) * C_ + c) * T_ + t4]) * e[s2];
    *reinterpret_cast<f32x4*>(&out[((size_t)b * C_ + c) * T_ + t4]) = acc * inv;
  }
}

// ---------------------------------------------------------------------------
extern "C" void kernel_launch(void* const* d_in, const int* in_sizes, int n_in,
                              void* d_out, int out_size, void* d_ws, size_t ws_size,
                              hipStream_t stream) {
  (void)in_sizes; (void)n_in; (void)out_size; (void)ws_size;
  const float* x  = (const float*)d_in[0];
  const float* Wk = (const float*)d_in[1];
  const float* bk = (const float*)d_in[2];
  const float* Wq = (const float*)d_in[3];
  const float* bq = (const float*)d_in[4];
  float* out = (float*)d_out;

  char* ws = (char*)d_ws;
  const size_t MB = 1024 * 1024;
  bf16*  Kb    = (bf16*)(ws);                 // 8 MB
  bf16*  Qb    = (bf16*)(ws + 8 * MB);        // 8 MB
  bf16*  Vf    = (bf16*)(ws + 16 * MB);       // 3 MB (fragment layout)
  bf16*  Wbf   = (bf16*)(ws + 19 * MB);       // 96 KB
  float* Opart = (float*)(ws + 20 * MB);      // NS*8*80*2048*4 = 20.97 MB
  float* mpart = (float*)(ws + 42 * MB);      // 256 KB
  float* lpart = (float*)(ws + 43 * MB);      // 256 KB

  dim3 blk(256);
  wconv_kernel<<<dim3(2, 12), blk, 0, stream>>>(Wk, bk, Wq, bq, Wbf);
  dim3 g1(T_ / 32, B_, 2);
  proj_kernel<<<g1, blk, 0, stream>>>(x, Wbf, Kb, Qb, Vf);
  attn_kernel<<<dim3(16 * NS * B_), blk, 0, stream>>>(Kb, Qb, Vf, Opart, mpart, lpart);
  dim3 g3(T_ / 64, B_);
  merge_kernel<<<g3, blk, 0, stream>>>(Opart, mpart, lpart, out);
}